// Round 10
// baseline (1249.720 us; speedup 1.0000x reference)
//
#include <hip/hip_runtime.h>
#include <hip/hip_bf16.h>
#include <stdint.h>

namespace {

constexpr int B = 8, T = 200, U = 50, D = 512, INNER = 640, VOCAB = 1024;
constexpr int M_TOTAL = B * T * U;          // 80000
constexpr int ROWS_E = B * T;               // 1600
constexpr int ROWS_D = B * U;               // 400
constexpr int ROWS_ED = ROWS_E + ROWS_D;    // 2000
constexpr int BM = 128;                     // grid 625
constexpr int CK = 128;                     // K-chunk; 5 chunks
constexpr int CHUNK_B = BM * CK * 2;        // 32 KiB per LDS buffer

typedef __bf16 bf16x8 __attribute__((ext_vector_type(8)));
typedef float  f32x4  __attribute__((ext_vector_type(4)));
typedef unsigned short u16;
typedef unsigned int   u32;

constexpr size_t ED_BYTES  = (size_t)ROWS_ED * INNER * 4;      // 5,120,000
// W2B right after ED in ws; total need ~6.5 MB.

__device__ __forceinline__ u16 f2bf(float f) {
  uint32_t u = __float_as_uint(f);
  uint32_t rounding = 0x7FFFu + ((u >> 16) & 1u);   // RNE
  return (u16)((u + rounding) >> 16);
}

__device__ __forceinline__ float fast_tanh(float x) {
  float e = __expf(2.0f * x);
  float r = __builtin_amdgcn_rcpf(e + 1.0f);
  return 1.0f - 2.0f * r;   // exact at both saturations
}

// ---------------------------------------------------------------------------
// k_prep: merged GEMM1 (ED) + W2 fragment pack (proven R5-R9).
//   blocks [0,500):   ED, 4 rows/block
//   blocks [500,756): W2B bf16 fragment pack
// Fragment f = ks*64+nf (1 KiB); lane l: {n = nf*16+(l&15), k = ks*32+(l>>4)*8+j}
// ---------------------------------------------------------------------------
__global__ __launch_bounds__(320) void k_prep(const float* __restrict__ enc,
                                              const float* __restrict__ dec,
                                              const float* __restrict__ W1,
                                              const float* __restrict__ b1,
                                              const float* __restrict__ W2,
                                              float* __restrict__ ED,
                                              u16* __restrict__ W2B) {
  if (blockIdx.x >= 500) {
    const int idx = (blockIdx.x - 500) * 320 + threadIdx.x;   // < 81920 exact
    const int lane = idx & 63;
    const int f = idx >> 6;
    const int ks = f >> 6;
    const int nf = f & 63;
    const int n = nf * 16 + (lane & 15);
    const int k = ks * 32 + (lane >> 4) * 8;
    u16 v[8];
#pragma unroll
    for (int j = 0; j < 8; ++j)
      v[j] = f2bf(W2[(size_t)(k + j) * VOCAB + n]);
    uint64_t lo = (uint64_t)v[0] | ((uint64_t)v[1] << 16) |
                  ((uint64_t)v[2] << 32) | ((uint64_t)v[3] << 48);
    uint64_t hi = (uint64_t)v[4] | ((uint64_t)v[5] << 16) |
                  ((uint64_t)v[6] << 32) | ((uint64_t)v[7] << 48);
    uint64_t* dst = reinterpret_cast<uint64_t*>(W2B + (size_t)idx * 8);
    dst[0] = lo;
    dst[1] = hi;
    return;
  }

  __shared__ float rows[4 * D];   // 8 KiB
  const int r0 = blockIdx.x * 4;
  const bool is_enc = (r0 < ROWS_E);
  const float* src = is_enc ? (enc + (size_t)r0 * D)
                            : (dec + (size_t)(r0 - ROWS_E) * D);
  for (int i = threadIdx.x; i < 4 * D; i += 320) rows[i] = src[i];
  __syncthreads();

  const int c0 = threadIdx.x, c1 = threadIdx.x + 320;
  float acc[4][2];
  const float bias0 = is_enc ? b1[c0] : 0.f;
  const float bias1 = is_enc ? b1[c1] : 0.f;
#pragma unroll
  for (int r = 0; r < 4; ++r) { acc[r][0] = bias0; acc[r][1] = bias1; }

  for (int d = 0; d < D; d += 8) {
    f32x4 rv[4][2];
#pragma unroll
    for (int r = 0; r < 4; ++r) {
      rv[r][0] = *reinterpret_cast<const f32x4*>(&rows[r * D + d]);
      rv[r][1] = *reinterpret_cast<const f32x4*>(&rows[r * D + d + 4]);
    }
#pragma unroll
    for (int dd = 0; dd < 8; ++dd) {
      const float w0 = W1[(size_t)(d + dd) * INNER + c0];
      const float w1 = W1[(size_t)(d + dd) * INNER + c1];
#pragma unroll
      for (int r = 0; r < 4; ++r) {
        const float x = rv[r][dd >> 2][dd & 3];
        acc[r][0] = fmaf(x, w0, acc[r][0]);
        acc[r][1] = fmaf(x, w1, acc[r][1]);
      }
    }
  }
#pragma unroll
  for (int r = 0; r < 4; ++r) {
    ED[(size_t)(r0 + r) * INNER + c0] = acc[r][0];
    ED[(size_t)(r0 + r) * INNER + c1] = acc[r][1];
  }
}

// ---------------------------------------------------------------------------
// k_main: out[128 x 1024] = tanh(E1+D1) @ W2 + b2  — tanh computed ONCE.
// 1024 thr = 16 waves (2x8), wave-tile 64x128, acc[4][8] = 128 VGPR.
// A: 5 K-chunks of 128 in fragment-order LDS double buffer (2 x 32 KiB);
//    R7-proven scheme: tanh(c+1) -> other buffer overlaps MFMA(c), ONE
//    barrier per chunk. B: direct from L2 (frag-packed W2B), demand
//    2.44 TB/s/XCD at MFMA pace (57% of L2 ceiling).
// Frag-order LDS: frag f = rowgrp*4 + kq (1 KiB, linear lane*16 -> 0 bank
// conflicts, no swizzle needed).
// ---------------------------------------------------------------------------
__global__ __launch_bounds__(1024, 4) void k_main(const float* __restrict__ ED,
                                                  const u16* __restrict__ W2B,
                                                  const float* __restrict__ b2,
                                                  float* __restrict__ out) {
  __shared__ u16 At[2][BM * CK];   // 2 x 32768 B
  const int tid = threadIdx.x;
  const int m0 = blockIdx.x * BM;

  // ---- tanh-writer statics: row = tid>>3 (0..127), g = tid&7 (16 k's) ----
  const int row = tid >> 3;
  const int g   = tid & 7;
  const int m = m0 + row;
  const int bb = m / (T * U);
  const int rem = m - bb * (T * U);
  const int tt = rem / U;
  const int uu = rem - tt * U;
  const float* Erow = ED + (size_t)(bb * T + tt) * INNER;
  const float* Drow = ED + (size_t)(ROWS_E + bb * U + uu) * INNER;
  // frag f = (row>>4)*4 + (g>>1); lane-in-frag = lhi*16 + (row&15),
  // lhi = (g&1)*2 + h  ->  byte(h) = f*1024 + (lhi*16+(row&15))*16
  const int wb0 = (((row >> 4) * 4 + (g >> 1)) << 10) +
                  (((g & 1) * 2) * 16 + (row & 15)) * 16;   // h=0; h=1: +256

  auto tanh_chunk = [&](int c, int bufsel) __attribute__((always_inline)) {
    char* dst = reinterpret_cast<char*>(At[bufsel]);
#pragma unroll
    for (int h = 0; h < 2; ++h) {
      const int kk = c * CK + g * 16 + h * 8;
      const f32x4 e0 = *reinterpret_cast<const f32x4*>(Erow + kk);
      const f32x4 e1 = *reinterpret_cast<const f32x4*>(Erow + kk + 4);
      const f32x4 d0 = *reinterpret_cast<const f32x4*>(Drow + kk);
      const f32x4 d1 = *reinterpret_cast<const f32x4*>(Drow + kk + 4);
      int4 pk;
      pk.x = (int)((u32)f2bf(fast_tanh(e0[0] + d0[0])) |
                   ((u32)f2bf(fast_tanh(e0[1] + d0[1])) << 16));
      pk.y = (int)((u32)f2bf(fast_tanh(e0[2] + d0[2])) |
                   ((u32)f2bf(fast_tanh(e0[3] + d0[3])) << 16));
      pk.z = (int)((u32)f2bf(fast_tanh(e1[0] + d1[0])) |
                   ((u32)f2bf(fast_tanh(e1[1] + d1[1])) << 16));
      pk.w = (int)((u32)f2bf(fast_tanh(e1[2] + d1[2])) |
                   ((u32)f2bf(fast_tanh(e1[3] + d1[3])) << 16));
      *reinterpret_cast<int4*>(dst + wb0 + h * 256) = pk;
    }
  };

  // ---- MFMA statics: 16 waves 2x8; wave (wr,wc) owns rows wr*64+, cols wc*128+ ----
  const int lane = tid & 63;
  const int w    = tid >> 6;
  const int wr = w >> 3, wc = w & 7;
  const int llo = lane & 15, lhi = lane >> 4;
  // B frag id = ksg*64 + (wc*8 + ni); u16 offset = id*512 + lane*8
  const u16* Bp = W2B + ((size_t)(wc * 8) << 9) + lane * 8;
  // A frag for (mi, kq): f = (wr*4+mi)*4 + kq
  const int albase = lane * 16;

  f32x4 acc[4][8];
#pragma unroll
  for (int mi = 0; mi < 4; ++mi)
#pragma unroll
    for (int ni = 0; ni < 8; ++ni) acc[mi][ni] = (f32x4){0.f, 0.f, 0.f, 0.f};

  tanh_chunk(0, 0);
  __syncthreads();

  for (int c = 0; c < 5; ++c) {
    const char* asrc = reinterpret_cast<const char*>(At[c & 1]);
    if (c < 4) tanh_chunk(c + 1, (c + 1) & 1);

#pragma unroll
    for (int kq = 0; kq < 4; ++kq) {
      bf16x8 a[4], bfr[8];
#pragma unroll
      for (int ni = 0; ni < 8; ++ni)
        bfr[ni] = *reinterpret_cast<const bf16x8*>(
            Bp + ((size_t)((c * 4 + kq) * 64 + ni) << 9));
#pragma unroll
      for (int mi = 0; mi < 4; ++mi)
        a[mi] = *reinterpret_cast<const bf16x8*>(
            asrc + ((((wr * 4 + mi) << 2) + kq) << 10) + albase);
#pragma unroll
      for (int mi = 0; mi < 4; ++mi)
#pragma unroll
        for (int ni = 0; ni < 8; ++ni)
          acc[mi][ni] = __builtin_amdgcn_mfma_f32_16x16x32_bf16(a[mi], bfr[ni], acc[mi][ni], 0, 0, 0);
    }
    __syncthreads();   // tanh(c+1) visible; buffer c reusable next iter
  }

  // ---- epilogue ----
  float b2v[8];
#pragma unroll
  for (int ni = 0; ni < 8; ++ni) b2v[ni] = b2[wc * 128 + ni * 16 + llo];

#pragma unroll
  for (int mi = 0; mi < 4; ++mi) {
#pragma unroll
    for (int q = 0; q < 4; ++q) {
      const int r = m0 + wr * 64 + mi * 16 + lhi * 4 + q;
      float* orow = out + (size_t)r * VOCAB + wc * 128 + llo;
#pragma unroll
      for (int ni = 0; ni < 8; ++ni)
        __builtin_nontemporal_store(acc[mi][ni][q] + b2v[ni], orow + ni * 16);
    }
  }
}

}  // namespace

extern "C" void kernel_launch(void* const* d_in, const int* in_sizes, int n_in,
                              void* d_out, int out_size, void* d_ws, size_t ws_size,
                              hipStream_t stream) {
  const float* enc = (const float*)d_in[0];
  const float* dec = (const float*)d_in[1];
  const float* W1  = (const float*)d_in[2];
  const float* b1  = (const float*)d_in[3];
  const float* W2  = (const float*)d_in[4];
  const float* b2  = (const float*)d_in[5];
  float* out = (float*)d_out;

  float* ED  = (float*)d_ws;
  u16*   W2B = (u16*)((char*)d_ws + ED_BYTES);

  hipLaunchKernelGGL(k_prep, dim3(756), dim3(320), 0, stream,
                     enc, dec, W1, b1, W2, ED, W2B);
  hipLaunchKernelGGL(k_main, dim3(M_TOTAL / BM), dim3(1024), 0, stream,
                     ED, W2B, b2, out);
}

// Round 11
// 214.064 us; speedup vs baseline: 5.8381x; 5.8381x over previous
//
#include <hip/hip_runtime.h>
#include <hip/hip_bf16.h>
#include <stdint.h>

namespace {

constexpr int B = 8, T = 200, U = 50, D = 512, INNER = 640, VOCAB = 1024;
constexpr int M_TOTAL = B * T * U;          // 80000
constexpr int ROWS_E = B * T;               // 1600
constexpr int ROWS_D = B * U;               // 400
constexpr int ROWS_ED = ROWS_E + ROWS_D;    // 2000
constexpr int BM = 128, BN = 512;           // grid (625, 2)
constexpr int CK = 128;                     // K-chunk; 5 chunks

typedef __bf16 bf16x8 __attribute__((ext_vector_type(8)));
typedef float  f32x4  __attribute__((ext_vector_type(4)));
typedef unsigned short u16;
typedef unsigned int   u32;

constexpr size_t ED_BYTES = (size_t)ROWS_ED * INNER * 4;   // 5,120,000

__device__ __forceinline__ u16 f2bf(float f) {
  uint32_t u = __float_as_uint(f);
  uint32_t rounding = 0x7FFFu + ((u >> 16) & 1u);   // RNE
  return (u16)((u + rounding) >> 16);
}

__device__ __forceinline__ float fast_tanh(float x) {
  float e = __expf(2.0f * x);
  float r = __builtin_amdgcn_rcpf(e + 1.0f);
  return 1.0f - 2.0f * r;   // exact at both saturations
}

// ---------------------------------------------------------------------------
// k_prep: merged GEMM1 (ED) + W2 fragment pack (proven R5-R10).
//   blocks [0,500):   ED, 4 rows/block
//   blocks [500,756): W2B bf16 fragment pack
// Fragment f = ks*64+nf (1 KiB); lane l: {n = nf*16+(l&15), k = ks*32+(l>>4)*8+j}
// ---------------------------------------------------------------------------
__global__ __launch_bounds__(320) void k_prep(const float* __restrict__ enc,
                                              const float* __restrict__ dec,
                                              const float* __restrict__ W1,
                                              const float* __restrict__ b1,
                                              const float* __restrict__ W2,
                                              float* __restrict__ ED,
                                              u16* __restrict__ W2B) {
  if (blockIdx.x >= 500) {
    const int idx = (blockIdx.x - 500) * 320 + threadIdx.x;   // < 81920 exact
    const int lane = idx & 63;
    const int f = idx >> 6;
    const int ks = f >> 6;
    const int nf = f & 63;
    const int n = nf * 16 + (lane & 15);
    const int k = ks * 32 + (lane >> 4) * 8;
    u16 v[8];
#pragma unroll
    for (int j = 0; j < 8; ++j)
      v[j] = f2bf(W2[(size_t)(k + j) * VOCAB + n]);
    uint64_t lo = (uint64_t)v[0] | ((uint64_t)v[1] << 16) |
                  ((uint64_t)v[2] << 32) | ((uint64_t)v[3] << 48);
    uint64_t hi = (uint64_t)v[4] | ((uint64_t)v[5] << 16) |
                  ((uint64_t)v[6] << 32) | ((uint64_t)v[7] << 48);
    uint64_t* dst = reinterpret_cast<uint64_t*>(W2B + (size_t)idx * 8);
    dst[0] = lo;
    dst[1] = hi;
    return;
  }

  __shared__ float rows[4 * D];   // 8 KiB
  const int r0 = blockIdx.x * 4;
  const bool is_enc = (r0 < ROWS_E);
  const float* src = is_enc ? (enc + (size_t)r0 * D)
                            : (dec + (size_t)(r0 - ROWS_E) * D);
  for (int i = threadIdx.x; i < 4 * D; i += 320) rows[i] = src[i];
  __syncthreads();

  const int c0 = threadIdx.x, c1 = threadIdx.x + 320;
  float acc[4][2];
  const float bias0 = is_enc ? b1[c0] : 0.f;
  const float bias1 = is_enc ? b1[c1] : 0.f;
#pragma unroll
  for (int r = 0; r < 4; ++r) { acc[r][0] = bias0; acc[r][1] = bias1; }

  for (int d = 0; d < D; d += 8) {
    f32x4 rv[4][2];
#pragma unroll
    for (int r = 0; r < 4; ++r) {
      rv[r][0] = *reinterpret_cast<const f32x4*>(&rows[r * D + d]);
      rv[r][1] = *reinterpret_cast<const f32x4*>(&rows[r * D + d + 4]);
    }
#pragma unroll
    for (int dd = 0; dd < 8; ++dd) {
      const float w0 = W1[(size_t)(d + dd) * INNER + c0];
      const float w1 = W1[(size_t)(d + dd) * INNER + c1];
#pragma unroll
      for (int r = 0; r < 4; ++r) {
        const float x = rv[r][dd >> 2][dd & 3];
        acc[r][0] = fmaf(x, w0, acc[r][0]);
        acc[r][1] = fmaf(x, w1, acc[r][1]);
      }
    }
  }
#pragma unroll
  for (int r = 0; r < 4; ++r) {
    ED[(size_t)(r0 + r) * INNER + c0] = acc[r][0];
    ED[(size_t)(r0 + r) * INNER + c1] = acc[r][1];
  }
}

// ---------------------------------------------------------------------------
// k_main: out[128 x 512 tile] = tanh(E1+D1) @ W2 + b2
// 1024 thr = 16 waves (2x8), wave-tile 64x64: acc[4][4]=64 AGPR + ~60 arch
// = 124 <= 128 combined cap at 4 waves/SIMD (R10's acc[4][8]=128 AGPR
// spilled 4.9 GB to scratch -> 1230 us; THE reg-budget rule:
// acc + arch <= 512 / wavesPerSIMD).
// A: 5 K-chunks of 128 in frag-order LDS dbuf (2 x 32 KiB); tanh(c+1)
// overlaps MFMA(c) across 4 waves/SIMD; ONE barrier per chunk.
// B: direct from L2 (frag-packed W2B), 2.44 TB/s/XCD demand at MFMA pace.
// ---------------------------------------------------------------------------
__global__ __launch_bounds__(1024, 4) void k_main(const float* __restrict__ ED,
                                                  const u16* __restrict__ W2B,
                                                  const float* __restrict__ b2,
                                                  float* __restrict__ out) {
  __shared__ u16 At[2][BM * CK];   // 2 x 32768 B
  const int tid = threadIdx.x;
  const int m0 = blockIdx.x * BM;
  const int n0 = blockIdx.y * BN;

  // ---- tanh-writer statics (verified in R10): row = tid>>3, g = tid&7 ----
  const int row = tid >> 3;
  const int g   = tid & 7;
  const int m = m0 + row;
  const int bb = m / (T * U);
  const int rem = m - bb * (T * U);
  const int tt = rem / U;
  const int uu = rem - tt * U;
  const float* Erow = ED + (size_t)(bb * T + tt) * INNER;
  const float* Drow = ED + (size_t)(ROWS_E + bb * U + uu) * INNER;
  // frag f = (row>>4)*4 + (g>>1); lane-in-frag = lhi*16 + (row&15),
  // lhi = (g&1)*2 + h  ->  byte(h) = f*1024 + (lhi*16+(row&15))*16
  const int wb0 = (((row >> 4) * 4 + (g >> 1)) << 10) +
                  (((g & 1) * 2) * 16 + (row & 15)) * 16;   // h=0; h=1: +256

  auto tanh_chunk = [&](int c, int bufsel) __attribute__((always_inline)) {
    char* dst = reinterpret_cast<char*>(At[bufsel]);
#pragma unroll
    for (int h = 0; h < 2; ++h) {
      const int kk = c * CK + g * 16 + h * 8;
      const f32x4 e0 = *reinterpret_cast<const f32x4*>(Erow + kk);
      const f32x4 e1 = *reinterpret_cast<const f32x4*>(Erow + kk + 4);
      const f32x4 d0 = *reinterpret_cast<const f32x4*>(Drow + kk);
      const f32x4 d1 = *reinterpret_cast<const f32x4*>(Drow + kk + 4);
      int4 pk;
      pk.x = (int)((u32)f2bf(fast_tanh(e0[0] + d0[0])) |
                   ((u32)f2bf(fast_tanh(e0[1] + d0[1])) << 16));
      pk.y = (int)((u32)f2bf(fast_tanh(e0[2] + d0[2])) |
                   ((u32)f2bf(fast_tanh(e0[3] + d0[3])) << 16));
      pk.z = (int)((u32)f2bf(fast_tanh(e1[0] + d1[0])) |
                   ((u32)f2bf(fast_tanh(e1[1] + d1[1])) << 16));
      pk.w = (int)((u32)f2bf(fast_tanh(e1[2] + d1[2])) |
                   ((u32)f2bf(fast_tanh(e1[3] + d1[3])) << 16));
      *reinterpret_cast<int4*>(dst + wb0 + h * 256) = pk;
    }
  };

  // ---- MFMA statics: 16 waves (2x8); wave (wr,wc): rows wr*64+, cols wc*64+ ----
  const int lane = tid & 63;
  const int w    = tid >> 6;
  const int wr = w >> 3, wc = w & 7;
  const int llo = lane & 15, lhi = lane >> 4;
  // B frag id = ks*64 + (n0/16 + wc*4 + ni); u16 offset = id*512 + lane*8
  const u16* Bp = W2B + ((size_t)((n0 >> 4) + wc * 4) << 9) + lane * 8;
  const int albase = lane * 16;

  f32x4 acc[4][4];
#pragma unroll
  for (int mi = 0; mi < 4; ++mi)
#pragma unroll
    for (int ni = 0; ni < 4; ++ni) acc[mi][ni] = (f32x4){0.f, 0.f, 0.f, 0.f};

  tanh_chunk(0, 0);
  __syncthreads();

  for (int c = 0; c < 5; ++c) {
    const char* asrc = reinterpret_cast<const char*>(At[c & 1]);
    if (c < 4) tanh_chunk(c + 1, (c + 1) & 1);

#pragma unroll
    for (int kq = 0; kq < 4; ++kq) {
      bf16x8 a[4], bfr[4];
#pragma unroll
      for (int ni = 0; ni < 4; ++ni)
        bfr[ni] = *reinterpret_cast<const bf16x8*>(
            Bp + ((size_t)((c * 4 + kq) * 64 + ni) << 9));
#pragma unroll
      for (int mi = 0; mi < 4; ++mi)
        a[mi] = *reinterpret_cast<const bf16x8*>(
            asrc + ((((wr * 4 + mi) << 2) + kq) << 10) + albase);
#pragma unroll
      for (int mi = 0; mi < 4; ++mi)
#pragma unroll
        for (int ni = 0; ni < 4; ++ni)
          acc[mi][ni] = __builtin_amdgcn_mfma_f32_16x16x32_bf16(a[mi], bfr[ni], acc[mi][ni], 0, 0, 0);
    }
    __syncthreads();   // tanh(c+1) visible; buffer c reusable next iter
  }

  // ---- epilogue ----
  float b2v[4];
#pragma unroll
  for (int ni = 0; ni < 4; ++ni) b2v[ni] = b2[n0 + wc * 64 + ni * 16 + llo];

#pragma unroll
  for (int mi = 0; mi < 4; ++mi) {
#pragma unroll
    for (int q = 0; q < 4; ++q) {
      const int r = m0 + wr * 64 + mi * 16 + lhi * 4 + q;
      float* orow = out + (size_t)r * VOCAB + n0 + wc * 64 + llo;
#pragma unroll
      for (int ni = 0; ni < 4; ++ni)
        __builtin_nontemporal_store(acc[mi][ni][q] + b2v[ni], orow + ni * 16);
    }
  }
}

}  // namespace

extern "C" void kernel_launch(void* const* d_in, const int* in_sizes, int n_in,
                              void* d_out, int out_size, void* d_ws, size_t ws_size,
                              hipStream_t stream) {
  const float* enc = (const float*)d_in[0];
  const float* dec = (const float*)d_in[1];
  const float* W1  = (const float*)d_in[2];
  const float* b1  = (const float*)d_in[3];
  const float* W2  = (const float*)d_in[4];
  const float* b2  = (const float*)d_in[5];
  float* out = (float*)d_out;

  float* ED  = (float*)d_ws;
  u16*   W2B = (u16*)((char*)d_ws + ED_BYTES);

  hipLaunchKernelGGL(k_prep, dim3(756), dim3(320), 0, stream,
                     enc, dec, W1, b1, W2, ED, W2B);
  hipLaunchKernelGGL(k_main, dim3(M_TOTAL / BM, VOCAB / BN), dim3(1024), 0, stream,
                     ED, W2B, b2, out);
}